// Round 14
// baseline (168.777 us; speedup 1.0000x reference)
//
#include <hip/hip_runtime.h>
#include <hip/hip_bf16.h>
#include <math.h>

typedef short short8 __attribute__((ext_vector_type(8)));
typedef short short4v __attribute__((ext_vector_type(4)));
typedef float f32x4 __attribute__((ext_vector_type(4)));

__device__ __forceinline__ short f2bf(float f) {
  union { float f; unsigned u; } v; v.f = f;
  unsigned r = v.u + 0x7FFFu + ((v.u >> 16) & 1u);
  return (short)(r >> 16);
}
__device__ __forceinline__ float bf2f(short s) {
  union { unsigned u; float f; } v; v.u = ((unsigned)(unsigned short)s) << 16;
  return v.f;
}

// -------- generic f32 -> bf16 cast, 4 elems/thread -----------------------
__global__ __launch_bounds__(256) void cast_kernel(const float* __restrict__ in,
                                                   short* __restrict__ out, int n4) {
  int i = blockIdx.x * blockDim.x + threadIdx.x;
  if (i < n4) {
    float4 v = ((const float4*)in)[i];
    short4v o;
    o.x = f2bf(v.x); o.y = f2bf(v.y); o.z = f2bf(v.z); o.w = f2bf(v.w);
    ((short4v*)out)[i] = o;
  }
}

// -------- v[n] = sum_k D[k,n] = sum_k 2cos(pi/2048*(2n+1)*k) --------------
// Deterministic 2-stage build (no float atomics).
__global__ __launch_bounds__(256) void vbuild(float* __restrict__ vpart) {
  int t = blockIdx.x * 256 + threadIdx.x;   // 8192: 8 k-chunks x 1024 n
  int n = t & 1023, ch = t >> 10;
  float coef = 1.5339807878856412e-03f * (float)(2 * n + 1);  // pi/2048*(2n+1)
  float s = 0.f;
  for (int k = ch * 128; k < ch * 128 + 128; ++k) s += cosf(coef * (float)k);
  vpart[(size_t)ch * 1024 + n] = 2.f * s;
}
__global__ __launch_bounds__(256) void vfold(const float* __restrict__ vpart,
                                             float* __restrict__ v) {
  int n = blockIdx.x * 256 + threadIdx.x;   // 1024
  float s = 0.f;
#pragma unroll
  for (int r = 0; r < 8; ++r) s += vpart[r * 1024 + n];
  v[n] = s;
}

// -------- DCT even/odd prep + closed-form LN stats ------------------------
// e[n]=x[n]+x[1023-n], o[n]=x[n]-x[1023-n]; per (b,c) row:
// mu = (v.x_row)/1024 ; E[freq^2] = 2*||x||^2 + (sum x)^2/512  (D^T D =
// 2N I + 2*11^T identity) ; rstd = rsqrt(E-mu^2+eps).
__global__ __launch_bounds__(256) void prep_eo(const float* __restrict__ x,
                                               const float* __restrict__ v,
                                               short* __restrict__ eo,
                                               float2* __restrict__ musd) {
  int t = blockIdx.x * 256 + threadIdx.x;     // 16384 rows * 128 thr
  int bc = t >> 7, n0 = (t & 127) * 4;        // n0 in [0,512)
  const float* xr = x + (size_t)bc * 1024;
  float4 f = *(const float4*)(xr + n0);
  float4 r = *(const float4*)(xr + 1020 - n0);
  short4v ef, of;
  ef.x = f2bf(f.x + r.w); ef.y = f2bf(f.y + r.z); ef.z = f2bf(f.z + r.y); ef.w = f2bf(f.w + r.x);
  of.x = f2bf(f.x - r.w); of.y = f2bf(f.y - r.z); of.z = f2bf(f.z - r.y); of.w = f2bf(f.w - r.x);
  *(short4v*)&eo[(size_t)bc * 512 + n0] = ef;
  *(short4v*)&eo[8388608 + (size_t)bc * 512 + n0] = of;

  float4 vf = *(const float4*)(v + n0);
  float4 vr = *(const float4*)(v + 1020 - n0);
  float s2 = f.x*f.x + f.y*f.y + f.z*f.z + f.w*f.w
           + r.x*r.x + r.y*r.y + r.z*r.z + r.w*r.w;
  float sx = f.x + f.y + f.z + f.w + r.x + r.y + r.z + r.w;
  float dt = f.x*vf.x + f.y*vf.y + f.z*vf.z + f.w*vf.w
           + r.x*vr.x + r.y*vr.y + r.z*vr.z + r.w*vr.w;
#pragma unroll
  for (int m = 1; m <= 32; m <<= 1) {
    s2 += __shfl_xor(s2, m);
    sx += __shfl_xor(sx, m);
    dt += __shfl_xor(dt, m);
  }
  __shared__ float red[2][2][4];
  int rowh = threadIdx.x >> 7, wv = (threadIdx.x >> 6) & 1;
  if ((threadIdx.x & 63) == 0) {
    red[rowh][wv][0] = s2; red[rowh][wv][1] = sx; red[rowh][wv][2] = dt;
  }
  __syncthreads();
  if ((threadIdx.x & 127) == 0) {
    float S2 = red[rowh][0][0] + red[rowh][1][0];
    float SX = red[rowh][0][1] + red[rowh][1][1];
    float DT = red[rowh][0][2] + red[rowh][1][2];
    float mu  = DT * (1.f / 1024.f);
    float ex2 = 2.f * S2 + SX * SX * (1.f / 512.f);
    float var = ex2 - mu * mu;                 // biased, like nn.LayerNorm
    float2 o; o.x = mu; o.y = rsqrtf(var + 1e-6f);
    musd[bc] = o;
  }
}

// -------- Deo[parity][k'][n] = 2*cos(pi/2048 * (2k'+parity) * (2n+1)) -----
__global__ __launch_bounds__(256) void build_Deo(short* __restrict__ D) {
  int t = blockIdx.x * 256 + threadIdx.x;     // 2*512*512 = 524288
  int parity = t >> 18, rem = t & 262143;
  int k2 = rem >> 9, n = rem & 511;
  const float s = 1.5339807878856412e-03f;    // pi/2048
  float arg = (s * (float)(2 * k2 + parity)) * (float)(2 * n + 1);
  D[t] = f2bf(2.0f * cosf(arg));
}

// ======== 256x128 BK=32 dbuf BT-GEMM, 4 waves (2Mx2N), 2 blocks/CU ========
// (r13 structure, unchanged schedule.)
// EPI 0: A=Deo(k'), B=eo; bz=parity; out row rr=2r+bz; LN applied IN
//        EPILOGUE: h = (v-mu_c)*rstd_c*lnw[rr] + lnb[rr]  (musd from prep).
// EPI 1: A=freqT(p,normalized), B=w1(o); relu -> z1t bf16.
// EPI 2: A=w2(o2), B=z1t(p); out = x * sigmoid(C), fp32.
template<int EPI>
__global__ __launch_bounds__(256, 2) void gemmF(
    const short* __restrict__ A, const short* __restrict__ B,
    void* __restrict__ Cout, const float* __restrict__ X,
    const float2* __restrict__ MS, const float* __restrict__ LNW,
    const float* __restrict__ LNB,
    int K, int NT, long strideA, long strideB)
{
  __shared__ short As[2][8192];    // 256 rows x 32 k
  __shared__ short Bs[2][4096];    // 128 rows x 32 k
  const int tid = threadIdx.x;     // 256
  const int l   = tid & 63;
  const int w   = tid >> 6;        // wave 0..3
  const int wm  = w >> 1;          // 0..1  (M: 128 rows each)
  const int wc  = w & 1;           // 0..1  (N: 64 cols each)
  const int lr  = l & 15;
  const int lhi = l >> 4;

  // ---- T1 bijective XCD swizzle (grids divisible by 8) ----
  const int nwg = gridDim.x, q = nwg >> 3, orig = blockIdx.x;
  const int wgid = (orig & 7) * q + (orig >> 3);
  int bx, by, bz;
  if (EPI == 0)      { bx = wgid & 1; bz = (wgid >> 1) & 1; by = wgid >> 2; }
  else if (EPI == 1) { by = wgid & 7; bx = (wgid >> 3) & 3; bz = wgid >> 5; }
  else               { bx = wgid & 1; by = (wgid >> 1) & 7; bz = wgid >> 4; }

  const long row0 = (long)bx * 256, col0 = (long)by * 128;
  const short* Ab = A + (size_t)bz * strideA + (size_t)row0 * K;
  const short* Bb = B + (size_t)bz * strideB + (size_t)col0 * K;

  // fragment read offsets: phys slot = lhi ^ ((row>>1)&3) = lhi ^ ((lr>>1)&3)
  const int sx    = (lhi ^ ((lr >> 1) & 3)) * 8;
  const int abase = (wm * 128 + lr) * 32;
  const int bbase = (wc * 64  + lr) * 32;

  f32x4 acc[8][4];
#pragma unroll
  for (int i = 0; i < 8; ++i)
#pragma unroll
    for (int j = 0; j < 4; ++j) acc[i][j] = (f32x4){0.f, 0.f, 0.f, 0.f};

#define GLL(SRC, DST) __builtin_amdgcn_global_load_lds(                      \
      (const __attribute__((address_space(1))) void*)(SRC),                  \
      (__attribute__((address_space(3))) void*)(DST), 16, 0, 0)

  // staging: chunk c -> row c>>2, phys slot c&3 (linear GLL dest); global
  // source k-col inverse-swizzled: s = (c&3) ^ ((row>>1)&3)
#define STAGE(KT, D) do {                                                    \
    const size_t kb_ = (size_t)(KT) * 32;                                    \
    _Pragma("unroll")                                                        \
    for (int r_ = 0; r_ < 4; ++r_) {                                         \
      int c_ = r_ * 256 + tid; int row_ = c_ >> 2; int sl_ = c_ & 3;         \
      int sc_ = (sl_ ^ ((row_ >> 1) & 3)) * 8;                               \
      GLL(Ab + (size_t)row_ * K + kb_ + sc_, &As[D][row_ * 32 + sl_ * 8]);   \
    }                                                                        \
    _Pragma("unroll")                                                        \
    for (int r_ = 0; r_ < 2; ++r_) {                                         \
      int c_ = r_ * 256 + tid; int row_ = c_ >> 2; int sl_ = c_ & 3;         \
      int sc_ = (sl_ ^ ((row_ >> 1) & 3)) * 8;                               \
      GLL(Bb + (size_t)row_ * K + kb_ + sc_, &Bs[D][row_ * 32 + sl_ * 8]);   \
    }                                                                        \
  } while (0)

#define LD8(PTR, OFF) (*(const short8*)&(PTR)[OFF])
#define MFMA(AV, BV, C) __builtin_amdgcn_mfma_f32_16x16x32_bf16(AV, BV, C, 0, 0, 0)
#define SBAR __builtin_amdgcn_s_barrier()
#define SCHB __builtin_amdgcn_sched_barrier(0)

#define MROW(MI, AV)                                                         \
    acc[MI][0] = MFMA(AV, b0, acc[MI][0]);                                   \
    acc[MI][1] = MFMA(AV, b1, acc[MI][1]);                                   \
    acc[MI][2] = MFMA(AV, b2, acc[MI][2]);                                   \
    acc[MI][3] = MFMA(AV, b3, acc[MI][3]);

  STAGE(0, 0);
  STAGE(1, 1);

  int cur = 0;
  for (int kt = 0; kt < NT; ++kt) {
    if (kt + 1 < NT) { asm volatile("s_waitcnt vmcnt(6)" ::: "memory"); }
    else             { asm volatile("s_waitcnt vmcnt(0)" ::: "memory"); }
    SCHB; SBAR;
    const short* Ad = As[cur];
    const short* Bd = Bs[cur];
    short8 a0, a1, a2, a3, a4, a5, a6, a7, b0, b1, b2, b3;
    a0 = LD8(Ad, abase + 0 * 512 + sx);
    a1 = LD8(Ad, abase + 1 * 512 + sx);
    b0 = LD8(Bd, bbase + 0 * 512 + sx);
    b1 = LD8(Bd, bbase + 1 * 512 + sx);
    b2 = LD8(Bd, bbase + 2 * 512 + sx);
    b3 = LD8(Bd, bbase + 3 * 512 + sx);
    a2 = LD8(Ad, abase + 2 * 512 + sx);
    a3 = LD8(Ad, abase + 3 * 512 + sx);
    a4 = LD8(Ad, abase + 4 * 512 + sx);
    a5 = LD8(Ad, abase + 5 * 512 + sx);
    a6 = LD8(Ad, abase + 6 * 512 + sx);
    a7 = LD8(Ad, abase + 7 * 512 + sx);
    SCHB;
    asm volatile("s_waitcnt lgkmcnt(6)" ::: "memory");   // a0,a1,b0-3 ready
    SCHB;
    __builtin_amdgcn_s_setprio(1);
    MROW(0, a0) MROW(1, a1)
    __builtin_amdgcn_s_setprio(0);
    SCHB;
    asm volatile("s_waitcnt lgkmcnt(0)" ::: "memory");   // all reads retired
    SCHB; SBAR;
    if (kt + 2 < NT) STAGE(kt + 2, cur);                 // overlapped by MFMAs
    SCHB;
    __builtin_amdgcn_s_setprio(1);
    MROW(2, a2) MROW(3, a3) MROW(4, a4) MROW(5, a5) MROW(6, a6) MROW(7, a7)
    __builtin_amdgcn_s_setprio(0);
    SCHB;
    cur ^= 1;
  }

  // ---------------- epilogue ----------------
#pragma unroll
  for (int mi = 0; mi < 8; ++mi) {
#pragma unroll
    for (int ni = 0; ni < 4; ++ni) {
      int cc = (int)col0 + wc * 64 + ni * 16 + lr;
      float2 ms;
      if (EPI == 0) ms = MS[cc];
#pragma unroll
      for (int j = 0; j < 4; ++j) {
        int r  = (int)row0 + wm * 128 + mi * 16 + lhi * 4 + j;
        float v = acc[mi][ni][j];
        if (EPI == 0) {
          int rr = r * 2 + bz;     // interleave even/odd k-rows
          float h = (v - ms.x) * ms.y * LNW[rr] + LNB[rr];
          ((short*)Cout)[((size_t)(cc >> 9) << 19) + (size_t)rr * 512 + (cc & 511)] = f2bf(h);
        } else if (EPI == 1) {
          ((short*)Cout)[(size_t)bz * 1048576 + (size_t)r * 1024 + cc] = f2bf(v > 0.f ? v : 0.f);
        } else {
          size_t idx = (size_t)bz * 524288 + (size_t)r * 1024 + cc;
          float g = 1.f / (1.f + __expf(-v));
          ((float*)Cout)[idx] = X[idx] * g;
        }
      }
    }
  }
#undef MROW
#undef MFMA
#undef LD8
#undef STAGE
#undef GLL
#undef SBAR
#undef SCHB
}

extern "C" void kernel_launch(void* const* d_in, const int* in_sizes, int n_in,
                              void* d_out, int out_size, void* d_ws, size_t ws_size,
                              hipStream_t stream) {
  const float* x    = (const float*)d_in[0];   // [32,512,1024]
  const float* w1   = (const float*)d_in[1];   // [1024,512]
  const float* w2   = (const float*)d_in[2];   // [512,1024]
  const float* ln_w = (const float*)d_in[3];   // [1024]
  const float* ln_b = (const float*)d_in[4];   // [1024]
  float* out = (float*)d_out;

  char* ws = (char*)d_ws;
  short* Deo    = (short*)(ws);                  //  1,048,576 B [2][512][512]
  short* w1_bf  = (short*)(ws + 1048576);        //  1,048,576 B
  short* w2_bf  = (short*)(ws + 2097152);        //  1,048,576 B
  short* freqT  = (short*)(ws + 3145728);        // 33,554,432 B [b][k][c] (=h)
  short* z1t    = (short*)(ws + 36700160);       // 67,108,864 B [b][p][o]
  short* eo     = z1t;                           // e/o alias z1t (dead by GEMM2)
  float* vpart  = (float*)(ws + 103809024);      //     32,768 B [8][1024]
  float* vvec   = (float*)(ws + 103874560);      //      4,096 B [1024]
  float2* musd  = (float2*)(ws + 104857600);     //    131,072 B [16384]
  // total ~105 MB

  vbuild<<<dim3(32), dim3(256), 0, stream>>>(vpart);
  vfold<<<dim3(4), dim3(256), 0, stream>>>(vpart, vvec);
  prep_eo<<<dim3(8192), dim3(256), 0, stream>>>(x, vvec, eo, musd);
  cast_kernel<<<dim3(512), dim3(256), 0, stream>>>(w1, w1_bf, 524288 / 4);
  cast_kernel<<<dim3(512), dim3(256), 0, stream>>>(w2, w2_bf, 524288 / 4);
  build_Deo<<<dim3(2048), dim3(256), 0, stream>>>(Deo);

  // GEMM1 (even/odd): freq rows 2k'+p; LN applied in epilogue -> freqT = h.
  gemmF<0><<<dim3(512), dim3(256), 0, stream>>>(
      Deo, eo, (void*)freqT, nullptr, musd, ln_w, ln_b, 512, 16, 262144, 8388608);

  // GEMM2: C[p,o] = sum_c h[b][p,c] * w1[o,c], relu -> z1t[b][p][o]
  gemmF<1><<<dim3(1024), dim3(256), 0, stream>>>(
      freqT, w1_bf, (void*)z1t, nullptr, nullptr, nullptr, nullptr, 512, 16, 524288, 0);

  // GEMM3: C[o2,p] = sum_j w2[o2,j] * z1t[b][p,j]; out = x * sigmoid(C)
  gemmF<2><<<dim3(512), dim3(256), 0, stream>>>(
      w2_bf, z1t, (void*)out, x, nullptr, nullptr, nullptr, 1024, 32, 0, 1048576);
}

// Round 15
// 156.719 us; speedup vs baseline: 1.0769x; 1.0769x over previous
//
#include <hip/hip_runtime.h>
#include <hip/hip_bf16.h>
#include <math.h>

typedef short short8 __attribute__((ext_vector_type(8)));
typedef short short4v __attribute__((ext_vector_type(4)));
typedef float f32x4 __attribute__((ext_vector_type(4)));

__device__ __forceinline__ short f2bf(float f) {
  union { float f; unsigned u; } v; v.f = f;
  unsigned r = v.u + 0x7FFFu + ((v.u >> 16) & 1u);
  return (short)(r >> 16);
}
__device__ __forceinline__ float bf2f(short s) {
  union { unsigned u; float f; } v; v.u = ((unsigned)(unsigned short)s) << 16;
  return v.f;
}

// -------- generic f32 -> bf16 cast, 4 elems/thread -----------------------
__global__ __launch_bounds__(256) void cast_kernel(const float* __restrict__ in,
                                                   short* __restrict__ out, int n4) {
  int i = blockIdx.x * blockDim.x + threadIdx.x;
  if (i < n4) {
    float4 v = ((const float4*)in)[i];
    short4v o;
    o.x = f2bf(v.x); o.y = f2bf(v.y); o.z = f2bf(v.z); o.w = f2bf(v.w);
    ((short4v*)out)[i] = o;
  }
}

// -------- DCT even/odd prep: e[n]=x[n]+x[1023-n], o[n]=x[n]-x[1023-n] -----
__global__ __launch_bounds__(256) void prep_eo(const float* __restrict__ x,
                                               short* __restrict__ eo) {
  int t = blockIdx.x * 256 + threadIdx.x;     // 16384 * 128
  int bc = t >> 7, n0 = (t & 127) * 4;        // n0 in [0,512)
  const float* xr = x + (size_t)bc * 1024;
  float4 f = *(const float4*)(xr + n0);
  float4 r = *(const float4*)(xr + 1020 - n0);
  short4v ef, of;
  ef.x = f2bf(f.x + r.w); ef.y = f2bf(f.y + r.z); ef.z = f2bf(f.z + r.y); ef.w = f2bf(f.w + r.x);
  of.x = f2bf(f.x - r.w); of.y = f2bf(f.y - r.z); of.z = f2bf(f.z - r.y); of.w = f2bf(f.w - r.x);
  *(short4v*)&eo[(size_t)bc * 512 + n0] = ef;
  *(short4v*)&eo[8388608 + (size_t)bc * 512 + n0] = of;
}

// -------- Deo[parity][k'][n] = 2*cos(pi/2048 * (2k'+parity) * (2n+1)) -----
__global__ __launch_bounds__(256) void build_Deo(short* __restrict__ D) {
  int t = blockIdx.x * 256 + threadIdx.x;     // 2*512*512 = 524288
  int parity = t >> 18, rem = t & 262143;
  int k2 = rem >> 9, n = rem & 511;
  const float s = 1.5339807878856412e-03f;    // pi/2048
  float arg = (s * (float)(2 * k2 + parity)) * (float)(2 * n + 1);
  D[t] = f2bf(2.0f * cosf(arg));
}

// -------- fold 4 row-block partials -> per-(b,c) mu, rstd -----------------
__global__ __launch_bounds__(256) void ln_stats(const float2* __restrict__ partial,
                                                float2* __restrict__ musd) {
  int n = blockIdx.x * 256 + threadIdx.x;   // 16384
  float S = 0.f, Q = 0.f;
#pragma unroll
  for (int r = 0; r < 4; ++r) {
    float2 p = partial[(size_t)r * 16384 + n];
    S += p.x; Q += p.y;
  }
  float mu  = S * (1.f / 1024.f);
  float var = Q * (1.f / 1024.f) - mu * mu;   // biased, like nn.LayerNorm
  float2 o; o.x = mu; o.y = rsqrtf(var + 1e-6f);
  musd[n] = o;
}

// -------- streaming LN apply: freqT[b][k][c] in place, short8/thread ------
__global__ __launch_bounds__(256) void ln_apply(short* __restrict__ freqT,
                                                const float2* __restrict__ musd,
                                                const float* __restrict__ lnw,
                                                const float* __restrict__ lnb) {
  int t = blockIdx.x * 256 + threadIdx.x;
  int c8 = t & 63;
  int k  = (t >> 6) & 1023;
  int b  = t >> 16;
  size_t idx = ((size_t)b << 19) + (size_t)k * 512 + (size_t)c8 * 8;
  short8 v = *(const short8*)&freqT[idx];
  float w  = lnw[k];
  float bb = lnb[k];
  const float2* ms = &musd[b * 512 + c8 * 8];
  short8 o;
#pragma unroll
  for (int j = 0; j < 8; ++j) {
    float f = bf2f(v[j]);
    float2 m = ms[j];
    o[j] = f2bf((f - m.x) * m.y * w + bb);
  }
  *(short8*)&freqT[idx] = o;
}

// ======== 256x128 BK=32 dbuf BT-GEMM (r13 structure) — used for GEMM1 =====
// Per-wave output 128x64 (acc[8][4]); LDS 48KB -> 2 blocks/CU; counted
// vmcnt(6)/lgkm(6) schedule; swizzle phys slot = logical ^ ((row>>1)&3).
// EPI 0: A=Deo(k'), B=eo; bz=parity; out row=2r+bz; LN partials slot bz*2+bx.
template<int EPI>
__global__ __launch_bounds__(256, 2) void gemmF(
    const short* __restrict__ A, const short* __restrict__ B,
    void* __restrict__ Cout, const float* __restrict__ X,
    float2* __restrict__ P, int K, int NT, long strideA, long strideB)
{
  __shared__ short As[2][8192];    // 256 rows x 32 k
  __shared__ short Bs[2][4096];    // 128 rows x 32 k
  const int tid = threadIdx.x;     // 256
  const int l   = tid & 63;
  const int w   = tid >> 6;        // wave 0..3
  const int wm  = w >> 1;          // 0..1  (M: 128 rows each)
  const int wc  = w & 1;           // 0..1  (N: 64 cols each)
  const int lr  = l & 15;
  const int lhi = l >> 4;

  const int nwg = gridDim.x, q = nwg >> 3, orig = blockIdx.x;
  const int wgid = (orig & 7) * q + (orig >> 3);
  int bx, by, bz;
  bx = wgid & 1; bz = (wgid >> 1) & 1; by = wgid >> 2;

  const long row0 = (long)bx * 256, col0 = (long)by * 128;
  const short* Ab = A + (size_t)bz * strideA + (size_t)row0 * K;
  const short* Bb = B + (size_t)bz * strideB + (size_t)col0 * K;

  const int sx    = (lhi ^ ((lr >> 1) & 3)) * 8;
  const int abase = (wm * 128 + lr) * 32;
  const int bbase = (wc * 64  + lr) * 32;

  f32x4 acc[8][4];
#pragma unroll
  for (int i = 0; i < 8; ++i)
#pragma unroll
    for (int j = 0; j < 4; ++j) acc[i][j] = (f32x4){0.f, 0.f, 0.f, 0.f};

#define GLL(SRC, DST) __builtin_amdgcn_global_load_lds(                      \
      (const __attribute__((address_space(1))) void*)(SRC),                  \
      (__attribute__((address_space(3))) void*)(DST), 16, 0, 0)

#define STAGE(KT, D) do {                                                    \
    const size_t kb_ = (size_t)(KT) * 32;                                    \
    _Pragma("unroll")                                                        \
    for (int r_ = 0; r_ < 4; ++r_) {                                         \
      int c_ = r_ * 256 + tid; int row_ = c_ >> 2; int sl_ = c_ & 3;         \
      int sc_ = (sl_ ^ ((row_ >> 1) & 3)) * 8;                               \
      GLL(Ab + (size_t)row_ * K + kb_ + sc_, &As[D][row_ * 32 + sl_ * 8]);   \
    }                                                                        \
    _Pragma("unroll")                                                        \
    for (int r_ = 0; r_ < 2; ++r_) {                                         \
      int c_ = r_ * 256 + tid; int row_ = c_ >> 2; int sl_ = c_ & 3;         \
      int sc_ = (sl_ ^ ((row_ >> 1) & 3)) * 8;                               \
      GLL(Bb + (size_t)row_ * K + kb_ + sc_, &Bs[D][row_ * 32 + sl_ * 8]);   \
    }                                                                        \
  } while (0)

#define LD8(PTR, OFF) (*(const short8*)&(PTR)[OFF])
#define MFMA(AV, BV, C) __builtin_amdgcn_mfma_f32_16x16x32_bf16(AV, BV, C, 0, 0, 0)
#define SBAR __builtin_amdgcn_s_barrier()
#define SCHB __builtin_amdgcn_sched_barrier(0)

#define MROW(MI, AV)                                                         \
    acc[MI][0] = MFMA(AV, b0, acc[MI][0]);                                   \
    acc[MI][1] = MFMA(AV, b1, acc[MI][1]);                                   \
    acc[MI][2] = MFMA(AV, b2, acc[MI][2]);                                   \
    acc[MI][3] = MFMA(AV, b3, acc[MI][3]);

  STAGE(0, 0);
  STAGE(1, 1);

  int cur = 0;
  for (int kt = 0; kt < NT; ++kt) {
    if (kt + 1 < NT) { asm volatile("s_waitcnt vmcnt(6)" ::: "memory"); }
    else             { asm volatile("s_waitcnt vmcnt(0)" ::: "memory"); }
    SCHB; SBAR;
    const short* Ad = As[cur];
    const short* Bd = Bs[cur];
    short8 a0, a1, a2, a3, a4, a5, a6, a7, b0, b1, b2, b3;
    a0 = LD8(Ad, abase + 0 * 512 + sx);
    a1 = LD8(Ad, abase + 1 * 512 + sx);
    b0 = LD8(Bd, bbase + 0 * 512 + sx);
    b1 = LD8(Bd, bbase + 1 * 512 + sx);
    b2 = LD8(Bd, bbase + 2 * 512 + sx);
    b3 = LD8(Bd, bbase + 3 * 512 + sx);
    a2 = LD8(Ad, abase + 2 * 512 + sx);
    a3 = LD8(Ad, abase + 3 * 512 + sx);
    a4 = LD8(Ad, abase + 4 * 512 + sx);
    a5 = LD8(Ad, abase + 5 * 512 + sx);
    a6 = LD8(Ad, abase + 6 * 512 + sx);
    a7 = LD8(Ad, abase + 7 * 512 + sx);
    SCHB;
    asm volatile("s_waitcnt lgkmcnt(6)" ::: "memory");   // a0,a1,b0-3 ready
    SCHB;
    __builtin_amdgcn_s_setprio(1);
    MROW(0, a0) MROW(1, a1)
    __builtin_amdgcn_s_setprio(0);
    SCHB;
    asm volatile("s_waitcnt lgkmcnt(0)" ::: "memory");   // all reads retired
    SCHB; SBAR;
    if (kt + 2 < NT) STAGE(kt + 2, cur);                 // overlapped by MFMAs
    SCHB;
    __builtin_amdgcn_s_setprio(1);
    MROW(2, a2) MROW(3, a3) MROW(4, a4) MROW(5, a5) MROW(6, a6) MROW(7, a7)
    __builtin_amdgcn_s_setprio(0);
    SCHB;
    cur ^= 1;
  }

  // ---------------- epilogue ----------------
  float sv[4], qv[4];
#pragma unroll
  for (int ni = 0; ni < 4; ++ni) { sv[ni] = 0.f; qv[ni] = 0.f; }

#pragma unroll
  for (int mi = 0; mi < 8; ++mi) {
#pragma unroll
    for (int ni = 0; ni < 4; ++ni) {
#pragma unroll
      for (int j = 0; j < 4; ++j) {
        int r  = (int)row0 + wm * 128 + mi * 16 + lhi * 4 + j;
        int cc = (int)col0 + wc * 64 + ni * 16 + lr;
        float v = acc[mi][ni][j];
        sv[ni] += v; qv[ni] += v * v;
        int rr = r * 2 + bz;     // interleave even/odd k-rows
        ((short*)Cout)[((size_t)(cc >> 9) << 19) + (size_t)rr * 512 + (cc & 511)] = f2bf(v);
      }
    }
  }

  {
    __syncthreads();
    float* redS = (float*)&As[0][0];       // [128 cols][8 contributors]
    float* redQ = redS + 1024;
    const int contrib = wm * 4 + lhi;      // 8 contributors cover 256 rows
#pragma unroll
    for (int ni = 0; ni < 4; ++ni) {
      int ccl = wc * 64 + ni * 16 + lr;
      redS[ccl * 8 + contrib] = sv[ni];
      redQ[ccl * 8 + contrib] = qv[ni];
    }
    __syncthreads();
    if (tid < 128) {
      float S = 0.f, Q = 0.f;
#pragma unroll
      for (int i = 0; i < 8; ++i) { S += redS[tid * 8 + i]; Q += redQ[tid * 8 + i]; }
      float2 o; o.x = S; o.y = Q;
      P[(size_t)(bz * 2 + bx) * 16384 + col0 + tid] = o;
    }
  }
#undef MROW
#undef MFMA
#undef LD8
#undef STAGE
#undef GLL
#undef SBAR
#undef SCHB
}

// ======== 128x128 dbuf BT-GEMM, 4 waves, 2 blocks/CU (r9 structure) =======
// Deep block queues (2048/1024 grids) — best measured for GEMM2/GEMM3.
// EPI 1: relu -> z1t bf16.  EPI 2: out = x * sigmoid(C), fp32 x.
template<int EPI>
__global__ __launch_bounds__(256, 2) void gemm128(
    const short* __restrict__ A, const short* __restrict__ B,
    void* __restrict__ Cout, const float* __restrict__ X,
    int K, int NT, long strideA, long strideB)
{
  __shared__ short As[2][8192];
  __shared__ short Bs[2][8192];
  const int tid = threadIdx.x;     // 256
  const int l   = tid & 63;
  const int w   = tid >> 6;        // wave 0..3
  const int wm  = w >> 1;          // 0..1
  const int wc  = w & 1;           // 0..1
  const int l7  = l & 7;
  const int lr  = l & 15;
  const int lhi = l >> 4;

  const int nwg = gridDim.x, q = nwg >> 3, orig = blockIdx.x;
  const int wgid = (orig & 7) * q + (orig >> 3);
  int bx, by, bz;
  if (EPI == 1) { by = wgid & 7; bx = (wgid >> 3) & 7; bz = wgid >> 6; }
  else          { bx = wgid & 3; by = (wgid >> 2) & 7; bz = wgid >> 5; }

  const long row0 = (long)bx * 128, col0 = (long)by * 128;
  const short* Ab = A + (size_t)bz * strideA + (size_t)row0 * K;
  const short* Bb = B + (size_t)bz * strideB + (size_t)col0 * K;

  const int rowb  = tid >> 3;                       // 0..31
  const int colel = ((tid & 7) ^ ((tid >> 3) & 7)) * 8;
  const int abase = (wm * 64 + lr) * 64;
  const int bbase = (wc * 64 + lr) * 64;
  const int s0 = ((lhi    ) ^ l7) * 8;
  const int s1 = ((lhi + 4) ^ l7) * 8;

  f32x4 acc[4][4];
#pragma unroll
  for (int i = 0; i < 4; ++i)
#pragma unroll
    for (int j = 0; j < 4; ++j) acc[i][j] = (f32x4){0.f, 0.f, 0.f, 0.f};

#define GLL(SRC, DST) __builtin_amdgcn_global_load_lds(                      \
      (const __attribute__((address_space(1))) void*)(SRC),                  \
      (__attribute__((address_space(3))) void*)(DST), 16, 0, 0)

#define STAGE(KT, D) do {                                                    \
    const size_t ko_ = (size_t)(KT) * 64 + colel;                            \
    _Pragma("unroll")                                                        \
    for (int r_ = 0; r_ < 4; ++r_)                                           \
      GLL(Ab + (size_t)(r_ * 32 + rowb) * K + ko_,                           \
          &As[D][(r_ * 32 + rowb) * 64 + (tid & 7) * 8]);                    \
    _Pragma("unroll")                                                        \
    for (int r_ = 0; r_ < 4; ++r_)                                           \
      GLL(Bb + (size_t)(r_ * 32 + rowb) * K + ko_,                           \
          &Bs[D][(r_ * 32 + rowb) * 64 + (tid & 7) * 8]);                    \
  } while (0)

#define LD8(PTR, OFF) (*(const short8*)&(PTR)[OFF])
#define MFMA(AV, BV, C) __builtin_amdgcn_mfma_f32_16x16x32_bf16(AV, BV, C, 0, 0, 0)
#define SBAR __builtin_amdgcn_s_barrier()
#define SCHB __builtin_amdgcn_sched_barrier(0)

#define MFMA16(A0, A1, A2, A3, B0, B1, B2, B3)                               \
    __builtin_amdgcn_s_setprio(1);                                           \
    acc[0][0]=MFMA(A0,B0,acc[0][0]); acc[0][1]=MFMA(A0,B1,acc[0][1]);        \
    acc[0][2]=MFMA(A0,B2,acc[0][2]); acc[0][3]=MFMA(A0,B3,acc[0][3]);        \
    acc[1][0]=MFMA(A1,B0,acc[1][0]); acc[1][1]=MFMA(A1,B1,acc[1][1]);        \
    acc[1][2]=MFMA(A1,B2,acc[1][2]); acc[1][3]=MFMA(A1,B3,acc[1][3]);        \
    acc[2][0]=MFMA(A2,B0,acc[2][0]); acc[2][1]=MFMA(A2,B1,acc[2][1]);        \
    acc[2][2]=MFMA(A2,B2,acc[2][2]); acc[2][3]=MFMA(A2,B3,acc[2][3]);        \
    acc[3][0]=MFMA(A3,B0,acc[3][0]); acc[3][1]=MFMA(A3,B1,acc[3][1]);        \
    acc[3][2]=MFMA(A3,B2,acc[3][2]); acc[3][3]=MFMA(A3,B3,acc[3][3]);        \
    __builtin_amdgcn_s_setprio(0);

  STAGE(0, 0);
  STAGE(1, 1);

  int cur = 0;
  for (int kt = 0; kt < NT; ++kt) {
    if (kt + 1 < NT) { asm volatile("s_waitcnt vmcnt(8)" ::: "memory"); }
    else             { asm volatile("s_waitcnt vmcnt(0)" ::: "memory"); }
    SCHB; SBAR;
    const short* Ad = As[cur];
    const short* Bd = Bs[cur];
    short8 a00, a01, a02, a03, b00, b01, b02, b03;
    short8 a10, a11, a12, a13, b10, b11, b12, b13;
    a00 = LD8(Ad, abase + 0 * 1024 + s0);
    a01 = LD8(Ad, abase + 1 * 1024 + s0);
    a02 = LD8(Ad, abase + 2 * 1024 + s0);
    a03 = LD8(Ad, abase + 3 * 1024 + s0);
    b00 = LD8(Bd, bbase + 0 * 1024 + s0);
    b01 = LD8(Bd, bbase + 1 * 1024 + s0);
    b02 = LD8(Bd, bbase + 2 * 1024 + s0);
    b03 = LD8(Bd, bbase + 3 * 1024 + s0);
    a10 = LD8(Ad, abase + 0 * 1024 + s1);
    a11 = LD8(Ad, abase + 1 * 1024 + s1);
    a12 = LD8(Ad, abase + 2 * 1024 + s1);
    a13 = LD8(Ad, abase + 3 * 1024 + s1);
    b10 = LD8(Bd, bbase + 0 * 1024 + s1);
    b11 = LD8(Bd, bbase + 1 * 1024 + s1);
    b12 = LD8(Bd, bbase + 2 * 1024 + s1);
    b13 = LD8(Bd, bbase + 3 * 1024 + s1);
    SCHB;
    asm volatile("s_waitcnt lgkmcnt(8)" ::: "memory");
    SCHB;
    MFMA16(a00, a01, a02, a03, b00, b01, b02, b03)
    SCHB;
    asm volatile("s_waitcnt lgkmcnt(0)" ::: "memory");
    SCHB; SBAR;
    if (kt + 2 < NT) STAGE(kt + 2, cur);
    SCHB;
    MFMA16(a10, a11, a12, a13, b10, b11, b12, b13)
    SCHB;
    cur ^= 1;
  }

  // ---------------- epilogue ----------------
#pragma unroll
  for (int mi = 0; mi < 4; ++mi) {
#pragma unroll
    for (int ni = 0; ni < 4; ++ni) {
#pragma unroll
      for (int j = 0; j < 4; ++j) {
        int r  = (int)row0 + wm * 64 + mi * 16 + lhi * 4 + j;
        int cc = (int)col0 + wc * 64 + ni * 16 + lr;
        float v = acc[mi][ni][j];
        if (EPI == 1) {
          ((short*)Cout)[(size_t)bz * 1048576 + (size_t)r * 1024 + cc] = f2bf(v > 0.f ? v : 0.f);
        } else {
          size_t idx = (size_t)bz * 524288 + (size_t)r * 1024 + cc;
          float g = 1.f / (1.f + __expf(-v));
          ((float*)Cout)[idx] = X[idx] * g;
        }
      }
    }
  }
#undef MFMA16
#undef MFMA
#undef LD8
#undef STAGE
#undef GLL
#undef SBAR
#undef SCHB
}

extern "C" void kernel_launch(void* const* d_in, const int* in_sizes, int n_in,
                              void* d_out, int out_size, void* d_ws, size_t ws_size,
                              hipStream_t stream) {
  const float* x    = (const float*)d_in[0];   // [32,512,1024]
  const float* w1   = (const float*)d_in[1];   // [1024,512]
  const float* w2   = (const float*)d_in[2];   // [512,1024]
  const float* ln_w = (const float*)d_in[3];   // [1024]
  const float* ln_b = (const float*)d_in[4];   // [1024]
  float* out = (float*)d_out;

  char* ws = (char*)d_ws;
  short* Deo    = (short*)(ws);                  //  1,048,576 B [2][512][512]
  short* w1_bf  = (short*)(ws + 1048576);        //  1,048,576 B
  short* w2_bf  = (short*)(ws + 2097152);        //  1,048,576 B
  short* freqT  = (short*)(ws + 3145728);        // 33,554,432 B [b][k][c]
  short* z1t    = (short*)(ws + 36700160);       // 67,108,864 B [b][p][o]
  short* eo     = z1t;                           // e/o alias z1t (dead by GEMM2)
  float2* part  = (float2*)(ws + 103809024);     //    524,288 B [4][16384]
  float2* musd  = (float2*)(ws + 104857600);     //    131,072 B [16384]
  // total ~105 MB

  prep_eo<<<dim3(8192), dim3(256), 0, stream>>>(x, eo);
  cast_kernel<<<dim3(512), dim3(256), 0, stream>>>(w1, w1_bf, 524288 / 4);
  cast_kernel<<<dim3(512), dim3(256), 0, stream>>>(w2, w2_bf, 524288 / 4);
  build_Deo<<<dim3(2048), dim3(256), 0, stream>>>(Deo);

  // GEMM1 (even/odd): C[k',(b,c)] = sum_n Deo[p][k',n]*eo[p][(b,c),n]
  // -> freqT rows 2k'+p, + LN partials. K=512, NT=16, grid 2bx*2p*128by.
  gemmF<0><<<dim3(512), dim3(256), 0, stream>>>(
      Deo, eo, (void*)freqT, nullptr, part, 512, 16, 262144, 8388608);

  // LN stats: fold 4 partials (2 parity x 2 bx) -> (mu, rstd) per (b,c)
  ln_stats<<<dim3(64), dim3(256), 0, stream>>>(part, musd);

  // LN apply: normalize freqT in place (streaming, vectorized)
  ln_apply<<<dim3(8192), dim3(256), 0, stream>>>(freqT, musd, ln_w, ln_b);

  // GEMM2: C[p,o] = sum_c Ht[b][p,c] * w1[o,c], relu -> z1t[b][p][o]
  gemm128<1><<<dim3(2048), dim3(256), 0, stream>>>(
      freqT, w1_bf, (void*)z1t, nullptr, 512, 8, 524288, 0);

  // GEMM3: C[o2,p] = sum_j w2[o2,j] * z1t[b][p,j]; out = x * sigmoid(C)
  gemm128<2><<<dim3(1024), dim3(256), 0, stream>>>(
      w2_bf, z1t, (void*)out, x, 1024, 16, 0, 1048576);
}